// Round 1
// baseline (345.720 us; speedup 1.0000x reference)
//
#include <hip/hip_runtime.h>
#include <math.h>

typedef __bf16 bf16x8 __attribute__((ext_vector_type(8)));
typedef _Float16 f16x8 __attribute__((ext_vector_type(8)));
typedef _Float16 f16x4 __attribute__((ext_vector_type(4)));
typedef float f32x4 __attribute__((ext_vector_type(4)));

__device__ __forceinline__ unsigned short f2bf(float f) {
  unsigned int u = __builtin_bit_cast(unsigned int, f);
  u += 0x7fffu + ((u >> 16) & 1u);
  return (unsigned short)(u >> 16);
}
__device__ __forceinline__ unsigned int pack2bf(float a, float b) {
  return (unsigned int)f2bf(a) | ((unsigned int)f2bf(b) << 16);
}

// ---------- bf16 MFMA GEMM + sigmoid + avgpool2 (unchanged since R3) ----------
#define GK_PADK 40
template <int WFP32, int XFP32>
__global__ __launch_bounds__(256) void gemm_mfma_sig_pool(
    const void* __restrict__ Wv, const float* __restrict__ bias,
    const void* __restrict__ Xv, void* __restrict__ Y,
    int K, int Np, int out_bf16) {
  __shared__ unsigned short Wt[64][GK_PADK];
  __shared__ unsigned short Xt[64][GK_PADK];
  const int tid = threadIdx.x;
  const int i_base = blockIdx.x * 64;
  const int b_base = blockIdx.y * 64;
  const int srow = tid >> 2, sseg = tid & 3;
  const int wv = tid >> 6, lane = tid & 63;
  const int wn = wv & 1, wb = wv >> 1;
  const int L15 = lane & 15, q = lane >> 4;

  f32x4 acc[2][2] = {};
  for (int k0 = 0; k0 < K; k0 += 32) {
    if (WFP32) {
      const float* Wf = (const float*)Wv;
      const float4 a = *(const float4*)&Wf[(size_t)(i_base + srow) * K + k0 + sseg * 8];
      const float4 b = *(const float4*)&Wf[(size_t)(i_base + srow) * K + k0 + sseg * 8 + 4];
      uint4 p = { pack2bf(a.x, a.y), pack2bf(a.z, a.w), pack2bf(b.x, b.y), pack2bf(b.z, b.w) };
      *(uint4*)&Wt[srow][sseg * 8] = p;
    } else {
      *(uint4*)&Wt[srow][sseg * 8] =
          *(const uint4*)&((const unsigned short*)Wv)[(size_t)(i_base + srow) * K + k0 + sseg * 8];
    }
    if (XFP32) {
      const float* Xf = (const float*)Xv;
      const float4 a = *(const float4*)&Xf[(size_t)(b_base + srow) * K + k0 + sseg * 8];
      const float4 b = *(const float4*)&Xf[(size_t)(b_base + srow) * K + k0 + sseg * 8 + 4];
      uint4 p = { pack2bf(a.x, a.y), pack2bf(a.z, a.w), pack2bf(b.x, b.y), pack2bf(b.z, b.w) };
      *(uint4*)&Xt[srow][sseg * 8] = p;
    } else {
      *(uint4*)&Xt[srow][sseg * 8] =
          *(const uint4*)&((const unsigned short*)Xv)[(size_t)(b_base + srow) * K + k0 + sseg * 8];
    }
    __syncthreads();
    bf16x8 a0 = *(const bf16x8*)&Wt[wn * 32 + L15][q * 8];
    bf16x8 a1 = *(const bf16x8*)&Wt[wn * 32 + 16 + L15][q * 8];
    bf16x8 b0 = *(const bf16x8*)&Xt[wb * 32 + L15][q * 8];
    bf16x8 b1 = *(const bf16x8*)&Xt[wb * 32 + 16 + L15][q * 8];
    acc[0][0] = __builtin_amdgcn_mfma_f32_16x16x32_bf16(a0, b0, acc[0][0], 0, 0, 0);
    acc[0][1] = __builtin_amdgcn_mfma_f32_16x16x32_bf16(a0, b1, acc[0][1], 0, 0, 0);
    acc[1][0] = __builtin_amdgcn_mfma_f32_16x16x32_bf16(a1, b0, acc[1][0], 0, 0, 0);
    acc[1][1] = __builtin_amdgcn_mfma_f32_16x16x32_bf16(a1, b1, acc[1][1], 0, 0, 0);
    __syncthreads();
  }

  const int nb0 = i_base + wn * 32;
  const int bc0 = b_base + wb * 32 + L15;
#pragma unroll
  for (int mg = 0; mg < 2; mg++) {
    const int nrow = nb0 + mg * 16 + q * 4;
    const float bi0 = bias[nrow], bi1 = bias[nrow + 1];
    const float bi2 = bias[nrow + 2], bi3 = bias[nrow + 3];
#pragma unroll
    for (int bg = 0; bg < 2; bg++) {
      const int b = bc0 + bg * 16;
      f32x4 A = acc[mg][bg];
      const float a0 = __builtin_amdgcn_rcpf(1.f + __expf(-(A[0] + bi0)));
      const float a1 = __builtin_amdgcn_rcpf(1.f + __expf(-(A[1] + bi1)));
      const float a2 = __builtin_amdgcn_rcpf(1.f + __expf(-(A[2] + bi2)));
      const float a3 = __builtin_amdgcn_rcpf(1.f + __expf(-(A[3] + bi3)));
      const float p0 = 0.5f * (a0 + a1), p1 = 0.5f * (a2 + a3);
      const int pidx = nrow >> 1;  // even
      if (out_bf16) {
        *(unsigned int*)&((unsigned short*)Y)[(size_t)b * Np + pidx] = pack2bf(p0, p1);
      } else {
        *(float2*)&((float*)Y)[(size_t)b * Np + pidx] = make_float2(p0, p1);
      }
    }
  }
}

// ---------- prep: Whh -> fp16, hid-interleaved rows, K-stride 128 ----------
// Perm row 4*hid+gate = Whh[gate*100+hid][0:100], zero-padded to k=128.
// (Now consumed as 4 full ktiles by lstm_mfma16 -- the zero pad makes the
// k in [100,128) region a no-op as long as h rows are zero there too.)
__global__ __launch_bounds__(256) void prep_whh(
    const float* __restrict__ Whh, const float* __restrict__ b3,
    _Float16* __restrict__ P) {
  const int idx = blockIdx.x * 256 + threadIdx.x;  // (row, chunk-of-8)
  if (idx >= 400 * 16) return;
  const int row = idx >> 4, ch = idx & 15;
  const int hid = row >> 2, gate = row & 3;
  const int src = gate * 100 + hid;
  f16x8 v;
#pragma unroll
  for (int j = 0; j < 8; j++) {
    const int k = ch * 8 + j;
    float f = 0.f;
    if (k < 100) f = Whh[(size_t)src * 100 + k];
    v[j] = (_Float16)f;
  }
  *(f16x8*)&P[(size_t)row * 128 + ch * 8] = v;
}

// ---------- MFMA LSTM (R17): 16 batches per block in the B columns ----------
// R16 diagnosis: 1 batch/block left B's 16 columns identical (15/16 MFMA
// waste) and forced gate-per-lane + cndmask-select + DPP-broadcast act
// (~70 VALU/wave/step for 100 cells). Restructure: grid=16 blocks x 16
// batches; C-frag mapping (col=lane&15=batch, row=4*quad+reg=gate of
// hid 4*tile+quad via the gate-interleaved P) puts all 4 gates of one
// (hid,batch) in one lane's 4 acc regs -> no selects, no DPP, all 64
// lanes active, one act chain per 64 cells. K back to 128 (4 ktiles):
// the fp32 k-tail folds into MFMA (bias rides in as the C input,
// Wih*x_t as 4 post-MFMA FMAs). h: LDS rows of 256B per batch with XOR
// swizzle byte^=((c&7)<<4) on BOTH b128 reads and b16 writes (else the
// 256B row stride is a 16-way bank conflict). All per-lane ds offsets
// are loop-invariant (hbuf ping-pong by pointer, unroll x2).
#define TSTEPS 256
#define SIG(zz) __builtin_amdgcn_rcpf(1.f + __expf(-(zz)))

__global__ __launch_bounds__(512, 2) void lstm_mfma16(
    const float* __restrict__ X, const _Float16* __restrict__ P,
    const float* __restrict__ Wih, const float* __restrict__ b3,
    const float* __restrict__ Wout, const float* __restrict__ bout,
    float* __restrict__ out) {
  const int b0 = blockIdx.x * 16;
  const int t = threadIdx.x;
  const int w = t >> 6, lane = t & 63;
  const int quad = lane >> 4, c = lane & 15;  // c = batch column
  const int TB = (w == 7) ? 21 : w * 3;       // tile base (25 tiles of 16 rows)
  const int NT = (w == 7) ? 4 : 3;            // tiles this wave owns

  __shared__ __align__(16) _Float16 hb[2][2048];  // [buf][batch(16)][k(128)]
  __shared__ float xq[TSTEPS * 16];               // [step][batch]
  __shared__ float red[512];

  // stage x transposed: xq[s][bb] = X[b0+bb][s]  (coalesced reads)
  for (int idx = t; idx < 16 * TSTEPS; idx += 512) {
    const int bb = idx >> 8, s = idx & 255;
    xq[s * 16 + bb] = X[(size_t)(b0 + bb) * TSTEPS + s];
  }
  // zero both h buffers incl. the k in [100,128) pad (must stay 0 forever)
  {
    const float4 z4 = {0.f, 0.f, 0.f, 0.f};
    ((float4*)hb)[t] = z4;  // 8192 B == 512 float4
  }

  // A fragments: tile J, row = TB*16+J*16+c, k = kt*32 + quad*8 + j
  f16x8 A[4][4];
#pragma unroll
  for (int J = 0; J < 4; J++)
    if (J < NT) {
#pragma unroll
      for (int kt = 0; kt < 4; kt++)
        A[J][kt] = *(const f16x8*)&P[(size_t)((TB + J) * 16 + c) * 128 + kt * 32 + quad * 8];
    }

  // per-lane row constants: lane handles hid = 4*(TB+J)+quad, gates r=0..3
  f32x4 b3p[4], wihp[4];
#pragma unroll
  for (int J = 0; J < 4; J++)
    if (J < NT) {
      const int hid = 4 * (TB + J) + quad;
#pragma unroll
      for (int r = 0; r < 4; r++) {
        const int src = r * 100 + hid;  // gate-major layout of b3/Wih
        b3p[J][r] = b3[src];
        wihp[J][r] = Wih[src];
      }
    }

  // loop-invariant swizzled LDS offsets (bytes within hb[buf])
  const int swz = (c & 7) << 4;
  int roff[4], woff[4];
#pragma unroll
  for (int kt = 0; kt < 4; kt++) roff[kt] = c * 256 + ((kt * 64 + quad * 16) ^ swz);
#pragma unroll
  for (int J = 0; J < 4; J++) woff[J] = c * 256 + ((8 * (TB + J) + 2 * quad) ^ swz);

  float cst[4] = {0.f, 0.f, 0.f, 0.f};
  __syncthreads();

#define STEP(CUR, NXT, XV)                                                    \
  {                                                                           \
    const char* hcb = (const char*)hb[CUR];                                   \
    char* hnb = (char*)hb[NXT];                                               \
    const f16x8 B0 = *(const f16x8*)(hcb + roff[0]);                          \
    const f16x8 B1 = *(const f16x8*)(hcb + roff[1]);                          \
    const f16x8 B2 = *(const f16x8*)(hcb + roff[2]);                          \
    const f16x8 B3 = *(const f16x8*)(hcb + roff[3]);                          \
    _Pragma("unroll")                                                         \
    for (int J = 0; J < 4; J++)                                               \
      if (J < NT) {                                                           \
        f32x4 z = b3p[J];                                                     \
        z = __builtin_amdgcn_mfma_f32_16x16x32_f16(A[J][0], B0, z, 0, 0, 0);  \
        z = __builtin_amdgcn_mfma_f32_16x16x32_f16(A[J][1], B1, z, 0, 0, 0);  \
        z = __builtin_amdgcn_mfma_f32_16x16x32_f16(A[J][2], B2, z, 0, 0, 0);  \
        z = __builtin_amdgcn_mfma_f32_16x16x32_f16(A[J][3], B3, z, 0, 0, 0);  \
        const float zi = fmaf(wihp[J][0], (XV), z[0]);                        \
        const float zf = fmaf(wihp[J][1], (XV), z[1]);                        \
        const float zg = fmaf(wihp[J][2], (XV), z[2]);                        \
        const float zo = fmaf(wihp[J][3], (XV), z[3]);                        \
        const float ai = SIG(zi);                                             \
        const float af = SIG(zf);                                             \
        const float ag = 2.f * SIG(2.f * zg) - 1.f;                           \
        const float ao = SIG(zo);                                             \
        cst[J] = fmaf(af, cst[J], ai * ag);                                   \
        const float th = 2.f * SIG(2.f * cst[J]) - 1.f;                       \
        *(_Float16*)(hnb + woff[J]) = (_Float16)(ao * th);                    \
      }                                                                       \
    __syncthreads();                                                         \
  }

  for (int s = 0; s < TSTEPS; s += 2) {
    const float xv0 = xq[s * 16 + c];
    const float xv1 = xq[s * 16 + 16 + c];
    STEP(0, 1, xv0);
    STEP(1, 0, xv1);
  }
#undef STEP

  // out[b0+cc] = dot(h_final, Wout) + bout; final h in hb[0] (256 even steps)
  {
    const int cc = t >> 5, j = t & 31;
    const char* hfb = (const char*)hb[0];
    const int sw = (cc & 7) << 4;
    float acc = 0.f;
#pragma unroll
    for (int m = 0; m < 4; m++) {
      const int hid = j + 32 * m;
      if (hid < 100) {
        const _Float16 hv = *(const _Float16*)(hfb + cc * 256 + ((2 * hid) ^ sw));
        acc += (float)hv * Wout[hid];
      }
    }
    red[t] = acc;
  }
  __syncthreads();
  if (t < 16) {
    float s = 0.f;
#pragma unroll
    for (int k = 0; k < 32; k++) s += red[t * 32 + k];
    out[b0 + t] = s + bout[0];
  }
}
#undef SIG

// ---------- launch ----------
extern "C" void kernel_launch(void* const* d_in, const int* in_sizes, int n_in,
                              void* d_out, int out_size, void* d_ws, size_t ws_size,
                              hipStream_t stream) {
  const float* x    = (const float*)d_in[0];   // (256,1024)
  const float* W1L  = (const float*)d_in[3];   // (1024,1024)
  const float* b1L  = (const float*)d_in[4];
  const float* W2L  = (const float*)d_in[7];   // (512,512)
  const float* b2L  = (const float*)d_in[8];
  const float* Wih3 = (const float*)d_in[15];  // (400,1)
  const float* Whh3 = (const float*)d_in[16];  // (400,100)
  const float* b3   = (const float*)d_in[17];  // (400,)
  const float* Wout = (const float*)d_in[18];  // (1,100)
  const float* bout = (const float*)d_in[19];  // (1,)
  float* out = (float*)d_out;                  // (256,)

  unsigned short* xl1b = (unsigned short*)d_ws;        // 256x512 bf16
  float* xl2 = (float*)(xl1b + (size_t)256 * 512);     // 256x256 f32
  _Float16* P = (_Float16*)(xl2 + (size_t)256 * 256);  // 400x128 fp16

  prep_whh<<<25, 256, 0, stream>>>(Whh3, b3, P);
  gemm_mfma_sig_pool<1, 1><<<dim3(16, 4), 256, 0, stream>>>(W1L, b1L, x, xl1b, 1024, 512, 1);
  gemm_mfma_sig_pool<1, 0><<<dim3(8, 4), 256, 0, stream>>>(W2L, b2L, xl1b, xl2, 512, 256, 0);
  lstm_mfma16<<<16, 512, 0, stream>>>(xl2, P, Wih3, b3, Wout, bout, out);
}

// Round 2
// 337.242 us; speedup vs baseline: 1.0251x; 1.0251x over previous
//
#include <hip/hip_runtime.h>
#include <math.h>

typedef __bf16 bf16x8 __attribute__((ext_vector_type(8)));
typedef _Float16 f16x8 __attribute__((ext_vector_type(8)));
typedef _Float16 f16x4 __attribute__((ext_vector_type(4)));
typedef float f32x4 __attribute__((ext_vector_type(4)));

__device__ __forceinline__ unsigned short f2bf(float f) {
  unsigned int u = __builtin_bit_cast(unsigned int, f);
  u += 0x7fffu + ((u >> 16) & 1u);
  return (unsigned short)(u >> 16);
}
__device__ __forceinline__ unsigned int pack2bf(float a, float b) {
  return (unsigned int)f2bf(a) | ((unsigned int)f2bf(b) << 16);
}

// ---------- bf16 MFMA GEMM + sigmoid + avgpool2 (unchanged since R3) ----------
#define GK_PADK 40
template <int WFP32, int XFP32>
__global__ __launch_bounds__(256) void gemm_mfma_sig_pool(
    const void* __restrict__ Wv, const float* __restrict__ bias,
    const void* __restrict__ Xv, void* __restrict__ Y,
    int K, int Np, int out_bf16) {
  __shared__ unsigned short Wt[64][GK_PADK];
  __shared__ unsigned short Xt[64][GK_PADK];
  const int tid = threadIdx.x;
  const int i_base = blockIdx.x * 64;
  const int b_base = blockIdx.y * 64;
  const int srow = tid >> 2, sseg = tid & 3;
  const int wv = tid >> 6, lane = tid & 63;
  const int wn = wv & 1, wb = wv >> 1;
  const int L15 = lane & 15, q = lane >> 4;

  f32x4 acc[2][2] = {};
  for (int k0 = 0; k0 < K; k0 += 32) {
    if (WFP32) {
      const float* Wf = (const float*)Wv;
      const float4 a = *(const float4*)&Wf[(size_t)(i_base + srow) * K + k0 + sseg * 8];
      const float4 b = *(const float4*)&Wf[(size_t)(i_base + srow) * K + k0 + sseg * 8 + 4];
      uint4 p = { pack2bf(a.x, a.y), pack2bf(a.z, a.w), pack2bf(b.x, b.y), pack2bf(b.z, b.w) };
      *(uint4*)&Wt[srow][sseg * 8] = p;
    } else {
      *(uint4*)&Wt[srow][sseg * 8] =
          *(const uint4*)&((const unsigned short*)Wv)[(size_t)(i_base + srow) * K + k0 + sseg * 8];
    }
    if (XFP32) {
      const float* Xf = (const float*)Xv;
      const float4 a = *(const float4*)&Xf[(size_t)(b_base + srow) * K + k0 + sseg * 8];
      const float4 b = *(const float4*)&Xf[(size_t)(b_base + srow) * K + k0 + sseg * 8 + 4];
      uint4 p = { pack2bf(a.x, a.y), pack2bf(a.z, a.w), pack2bf(b.x, b.y), pack2bf(b.z, b.w) };
      *(uint4*)&Xt[srow][sseg * 8] = p;
    } else {
      *(uint4*)&Xt[srow][sseg * 8] =
          *(const uint4*)&((const unsigned short*)Xv)[(size_t)(b_base + srow) * K + k0 + sseg * 8];
    }
    __syncthreads();
    bf16x8 a0 = *(const bf16x8*)&Wt[wn * 32 + L15][q * 8];
    bf16x8 a1 = *(const bf16x8*)&Wt[wn * 32 + 16 + L15][q * 8];
    bf16x8 b0 = *(const bf16x8*)&Xt[wb * 32 + L15][q * 8];
    bf16x8 b1 = *(const bf16x8*)&Xt[wb * 32 + 16 + L15][q * 8];
    acc[0][0] = __builtin_amdgcn_mfma_f32_16x16x32_bf16(a0, b0, acc[0][0], 0, 0, 0);
    acc[0][1] = __builtin_amdgcn_mfma_f32_16x16x32_bf16(a0, b1, acc[0][1], 0, 0, 0);
    acc[1][0] = __builtin_amdgcn_mfma_f32_16x16x32_bf16(a1, b0, acc[1][0], 0, 0, 0);
    acc[1][1] = __builtin_amdgcn_mfma_f32_16x16x32_bf16(a1, b1, acc[1][1], 0, 0, 0);
    __syncthreads();
  }

  const int nb0 = i_base + wn * 32;
  const int bc0 = b_base + wb * 32 + L15;
#pragma unroll
  for (int mg = 0; mg < 2; mg++) {
    const int nrow = nb0 + mg * 16 + q * 4;
    const float bi0 = bias[nrow], bi1 = bias[nrow + 1];
    const float bi2 = bias[nrow + 2], bi3 = bias[nrow + 3];
#pragma unroll
    for (int bg = 0; bg < 2; bg++) {
      const int b = bc0 + bg * 16;
      f32x4 A = acc[mg][bg];
      const float a0 = __builtin_amdgcn_rcpf(1.f + __expf(-(A[0] + bi0)));
      const float a1 = __builtin_amdgcn_rcpf(1.f + __expf(-(A[1] + bi1)));
      const float a2 = __builtin_amdgcn_rcpf(1.f + __expf(-(A[2] + bi2)));
      const float a3 = __builtin_amdgcn_rcpf(1.f + __expf(-(A[3] + bi3)));
      const float p0 = 0.5f * (a0 + a1), p1 = 0.5f * (a2 + a3);
      const int pidx = nrow >> 1;  // even
      if (out_bf16) {
        *(unsigned int*)&((unsigned short*)Y)[(size_t)b * Np + pidx] = pack2bf(p0, p1);
      } else {
        *(float2*)&((float*)Y)[(size_t)b * Np + pidx] = make_float2(p0, p1);
      }
    }
  }
}

// ---------- prep: Whh -> fp16, hid-interleaved rows, K-stride 128 ----------
// Perm row 4*hid+gate = Whh[gate*100+hid][0:100], zero-padded to k=128.
// The zero pad (k in [100,128)) is load-bearing: lstm_mfma16's ktile-3
// broadcast-read trick relies on A rows being 0 for k >= 104.
__global__ __launch_bounds__(256) void prep_whh(
    const float* __restrict__ Whh, const float* __restrict__ b3,
    _Float16* __restrict__ P) {
  const int idx = blockIdx.x * 256 + threadIdx.x;  // (row, chunk-of-8)
  if (idx >= 400 * 16) return;
  const int row = idx >> 4, ch = idx & 15;
  const int hid = row >> 2, gate = row & 3;
  const int src = gate * 100 + hid;
  f16x8 v;
#pragma unroll
  for (int j = 0; j < 8; j++) {
    const int k = ch * 8 + j;
    float f = 0.f;
    if (k < 100) f = Whh[(size_t)src * 100 + k];
    v[j] = (_Float16)f;
  }
  *(f16x8*)&P[(size_t)row * 128 + ch * 8] = v;
}

// ---------- MFMA LSTM (R18): 16 waves, trans-trim, B3 broadcast ----------
// R17 post-mortem: 16-batch blocks concentrated the act's fixed pipe cost
// (1600 cells x ~10 quarter-rate trans ~= 500cy/SIMD/step + 400cy VALU +
// ~380cy LDS) on 16 CUs with only 2 waves/SIMD to hide ~70cy ds_read +
// 4-deep MFMA chain + ~150cy act chains -> 1920cy/step measured vs ~600cy
// pipe floor. R18 keeps the lane-dense mapping and:
//  (1) 1024 threads (16 waves, 4/SIMD): waves 0-8 own 2 tiles, 9-15 own 1
//      -> halves per-wave issue, 2x waves to fill latency bubbles.
//  (2) ktile-3 B read: ALL quads use quad0's address (LDS broadcast, 2cy
//      instead of ~12cy). Quads 1-3 get h[96..103] at k-slots 104..127
//      where A == 0 (prep_whh zero-pad) -> product unchanged.
//  (3) MFMA chain split za/zb (depth 4 -> 2 + one add).
//  (4) act trans 10 -> 8 per cell: sig(zi)*tanh(zg) and sig(zo)*tanh(c)
//      each as (1-E2)*rcp((1+E1)*(1+E2)) -- same exps, one shared rcp.
#define TSTEPS 256

__global__ __launch_bounds__(1024, 4) void lstm_mfma16(
    const float* __restrict__ X, const _Float16* __restrict__ P,
    const float* __restrict__ Wih, const float* __restrict__ b3,
    const float* __restrict__ Wout, const float* __restrict__ bout,
    float* __restrict__ out) {
  const int b0 = blockIdx.x * 16;
  const int t = threadIdx.x;
  const int w = t >> 6, lane = t & 63;
  const int quad = lane >> 4, c = lane & 15;      // c = batch column
  const int TB = (w < 9) ? 2 * w : 9 + w;         // tile base (25 tiles)
  const int NT = (w < 9) ? 2 : 1;                 // tiles this wave owns

  __shared__ __align__(16) _Float16 hb[2][2048];  // [buf][batch(16)][k(128)]
  __shared__ float xq[TSTEPS * 16];               // [step][batch]
  __shared__ float red[1024];

  // stage x transposed: xq[s][bb] = X[b0+bb][s]
  for (int idx = t; idx < 16 * TSTEPS; idx += 1024) {
    const int bb = idx >> 8, s = idx & 255;
    xq[s * 16 + bb] = X[(size_t)(b0 + bb) * TSTEPS + s];
  }
  // zero both h buffers incl. the k in [100,128) pad (must stay 0 forever)
  if (t < 512) {
    const float4 z4 = {0.f, 0.f, 0.f, 0.f};
    ((float4*)hb)[t] = z4;  // 8192 B == 512 float4
  }

  // A fragments: tile TB+J, row = (TB+J)*16+c, k = kt*32 + quad*8 + j
  f16x8 A[2][4];
#pragma unroll
  for (int J = 0; J < 2; J++)
    if (J < NT) {
#pragma unroll
      for (int kt = 0; kt < 4; kt++)
        A[J][kt] = *(const f16x8*)&P[(size_t)((TB + J) * 16 + c) * 128 + kt * 32 + quad * 8];
    }

  // per-lane row constants: lane handles hid = 4*(TB+J)+quad, gates r=0..3
  f32x4 b3p[2], wihp[2];
#pragma unroll
  for (int J = 0; J < 2; J++)
    if (J < NT) {
      const int hid = 4 * (TB + J) + quad;
#pragma unroll
      for (int r = 0; r < 4; r++) {
        const int src = r * 100 + hid;  // gate-major layout of b3/Wih
        b3p[J][r] = b3[src];
        wihp[J][r] = Wih[src];
      }
    }

  // loop-invariant swizzled LDS byte offsets. XOR bits 4-6 permute 16B
  // blocks wholesale, so b128 reads stay contiguous images of pre-swizzle
  // 16B chunks. roff[3]: quad0's address for ALL quads (broadcast).
  const int swz = (c & 7) << 4;
  int roff[4], woff[2];
#pragma unroll
  for (int kt = 0; kt < 3; kt++) roff[kt] = c * 256 + ((kt * 64 + quad * 16) ^ swz);
  roff[3] = c * 256 + (192 ^ swz);
#pragma unroll
  for (int J = 0; J < 2; J++) woff[J] = c * 256 + ((8 * (TB + J) + 2 * quad) ^ swz);

  float cst[2] = {0.f, 0.f};
  __syncthreads();

#define STEP(CUR, NXT, XV)                                                    \
  {                                                                           \
    const char* hcb = (const char*)hb[CUR];                                   \
    char* hnb = (char*)hb[NXT];                                               \
    const f16x8 B0 = *(const f16x8*)(hcb + roff[0]);                          \
    const f16x8 B1 = *(const f16x8*)(hcb + roff[1]);                          \
    const f16x8 B2 = *(const f16x8*)(hcb + roff[2]);                          \
    const f16x8 B3 = *(const f16x8*)(hcb + roff[3]);                          \
    _Pragma("unroll")                                                         \
    for (int J = 0; J < 2; J++)                                               \
      if (J < NT) {                                                           \
        f32x4 za = b3p[J];                                                    \
        f32x4 zb = {0.f, 0.f, 0.f, 0.f};                                      \
        za = __builtin_amdgcn_mfma_f32_16x16x32_f16(A[J][0], B0, za, 0, 0, 0);\
        zb = __builtin_amdgcn_mfma_f32_16x16x32_f16(A[J][1], B1, zb, 0, 0, 0);\
        za = __builtin_amdgcn_mfma_f32_16x16x32_f16(A[J][2], B2, za, 0, 0, 0);\
        zb = __builtin_amdgcn_mfma_f32_16x16x32_f16(A[J][3], B3, zb, 0, 0, 0);\
        const f32x4 z = za + zb;                                              \
        const float zi = fmaf(wihp[J][0], (XV), z[0]);                        \
        const float zf = fmaf(wihp[J][1], (XV), z[1]);                        \
        const float zg = fmaf(wihp[J][2], (XV), z[2]);                        \
        const float zo = fmaf(wihp[J][3], (XV), z[3]);                        \
        const float Ei = __expf(-zi);                                         \
        const float Ef = fmaf = 0.f, Eg0 = 0.f; /* placeholder no-op */       \
        (void)Ef; (void)Eg0;                                                  \
      }                                                                       \
  }
#undef STEP

#define STEP(CUR, NXT, XV)                                                    \
  {                                                                           \
    const char* hcb = (const char*)hb[CUR];                                   \
    char* hnb = (char*)hb[NXT];                                               \
    const f16x8 B0 = *(const f16x8*)(hcb + roff[0]);                          \
    const f16x8 B1 = *(const f16x8*)(hcb + roff[1]);                          \
    const f16x8 B2 = *(const f16x8*)(hcb + roff[2]);                          \
    const f16x8 B3 = *(const f16x8*)(hcb + roff[3]);                          \
    _Pragma("unroll")                                                         \
    for (int J = 0; J < 2; J++)                                               \
      if (J < NT) {                                                           \
        f32x4 za = b3p[J];                                                    \
        f32x4 zb = {0.f, 0.f, 0.f, 0.f};                                      \
        za = __builtin_amdgcn_mfma_f32_16x16x32_f16(A[J][0], B0, za, 0, 0, 0);\
        zb = __builtin_amdgcn_mfma_f32_16x16x32_f16(A[J][1], B1, zb, 0, 0, 0);\
        za = __builtin_amdgcn_mfma_f32_16x16x32_f16(A[J][2], B2, za, 0, 0, 0);\
        zb = __builtin_amdgcn_mfma_f32_16x16x32_f16(A[J][3], B3, zb, 0, 0, 0);\
        const f32x4 z = za + zb;                                              \
        const float zi = fmaf(wihp[J][0], (XV), z[0]);                        \
        const float zf = fmaf(wihp[J][1], (XV), z[1]);                        \
        const float zg = fmaf(wihp[J][2], (XV), z[2]);                        \
        const float zo = fmaf(wihp[J][3], (XV), z[3]);                        \
        const float Ei = __expf(-zi);                                         \
        const float Ef = __expf(-zf);                                         \
        const float Eg = __expf(-2.f * zg);                                   \
        const float Eo = __expf(-zo);                                         \
        const float ig = (1.f - Eg) *                                         \
            __builtin_amdgcn_rcpf((1.f + Ei) * (1.f + Eg));                   \
        const float af = __builtin_amdgcn_rcpf(1.f + Ef);                     \
        cst[J] = fmaf(af, cst[J], ig);                                        \
        const float Ec = __expf(-2.f * cst[J]);                               \
        const float hv = (1.f - Ec) *                                         \
            __builtin_amdgcn_rcpf((1.f + Eo) * (1.f + Ec));                   \
        *(_Float16*)(hnb + woff[J]) = (_Float16)hv;                           \
      }                                                                       \
    __syncthreads();                                                          \
  }

  for (int s = 0; s < TSTEPS; s += 2) {
    const float xv0 = xq[s * 16 + c];
    const float xv1 = xq[s * 16 + 16 + c];
    STEP(0, 1, xv0);
    STEP(1, 0, xv1);
  }
#undef STEP

  // out[b0+cc] = dot(h_final, Wout) + bout; final h in hb[0] (256 even steps)
  {
    const int cc = t >> 6, j = t & 63;
    const char* hfb = (const char*)hb[0];
    const int sw = (cc & 7) << 4;
    float acc = 0.f;
    {
      const _Float16 hv = *(const _Float16*)(hfb + cc * 256 + ((2 * j) ^ sw));
      acc = (float)hv * Wout[j];
    }
    if (j + 64 < 100) {
      const _Float16 hv = *(const _Float16*)(hfb + cc * 256 + ((2 * (j + 64)) ^ sw));
      acc += (float)hv * Wout[j + 64];
    }
    red[t] = acc;
  }
  __syncthreads();
  if (t < 16) {
    float s = 0.f;
#pragma unroll
    for (int k = 0; k < 64; k++) s += red[t * 64 + k];
    out[b0 + t] = s + bout[0];
  }
}

// ---------- launch ----------
extern "C" void kernel_launch(void* const* d_in, const int* in_sizes, int n_in,
                              void* d_out, int out_size, void* d_ws, size_t ws_size,
                              hipStream_t stream) {
  const float* x    = (const float*)d_in[0];   // (256,1024)
  const float* W1L  = (const float*)d_in[3];   // (1024,1024)
  const float* b1L  = (const float*)d_in[4];
  const float* W2L  = (const float*)d_in[7];   // (512,512)
  const float* b2L  = (const float*)d_in[8];
  const float* Wih3 = (const float*)d_in[15];  // (400,1)
  const float* Whh3 = (const float*)d_in[16];  // (400,100)
  const float* b3   = (const float*)d_in[17];  // (400,)
  const float* Wout = (const float*)d_in[18];  // (1,100)
  const float* bout = (const float*)d_in[19];  // (1,)
  float* out = (float*)d_out;                  // (256,)

  unsigned short* xl1b = (unsigned short*)d_ws;        // 256x512 bf16
  float* xl2 = (float*)(xl1b + (size_t)256 * 512);     // 256x256 f32
  _Float16* P = (_Float16*)(xl2 + (size_t)256 * 256);  // 400x128 fp16

  prep_whh<<<25, 256, 0, stream>>>(Whh3, b3, P);
  gemm_mfma_sig_pool<1, 1><<<dim3(16, 4), 256, 0, stream>>>(W1L, b1L, x, xl1b, 1024, 512, 1);
  gemm_mfma_sig_pool<1, 0><<<dim3(8, 4), 256, 0, stream>>>(W2L, b2L, xl1b, xl2, 512, 256, 0);
  lstm_mfma16<<<16, 1024, 0, stream>>>(xl2, P, Wih3, b3, Wout, bout, out);
}

// Round 4
// 271.600 us; speedup vs baseline: 1.2729x; 1.2417x over previous
//
#include <hip/hip_runtime.h>
#include <math.h>

typedef __bf16 bf16x8 __attribute__((ext_vector_type(8)));
typedef _Float16 f16x8 __attribute__((ext_vector_type(8)));
typedef _Float16 f16x4 __attribute__((ext_vector_type(4)));
typedef float f32x4 __attribute__((ext_vector_type(4)));

__device__ __forceinline__ unsigned short f2bf(float f) {
  unsigned int u = __builtin_bit_cast(unsigned int, f);
  u += 0x7fffu + ((u >> 16) & 1u);
  return (unsigned short)(u >> 16);
}
__device__ __forceinline__ unsigned int pack2bf(float a, float b) {
  return (unsigned int)f2bf(a) | ((unsigned int)f2bf(b) << 16);
}

// ---------- bf16 MFMA GEMM + sigmoid + avgpool2 (unchanged since R3) ----------
#define GK_PADK 40
template <int WFP32, int XFP32>
__global__ __launch_bounds__(256) void gemm_mfma_sig_pool(
    const void* __restrict__ Wv, const float* __restrict__ bias,
    const void* __restrict__ Xv, void* __restrict__ Y,
    int K, int Np, int out_bf16) {
  __shared__ unsigned short Wt[64][GK_PADK];
  __shared__ unsigned short Xt[64][GK_PADK];
  const int tid = threadIdx.x;
  const int i_base = blockIdx.x * 64;
  const int b_base = blockIdx.y * 64;
  const int srow = tid >> 2, sseg = tid & 3;
  const int wv = tid >> 6, lane = tid & 63;
  const int wn = wv & 1, wb = wv >> 1;
  const int L15 = lane & 15, q = lane >> 4;

  f32x4 acc[2][2] = {};
  for (int k0 = 0; k0 < K; k0 += 32) {
    if (WFP32) {
      const float* Wf = (const float*)Wv;
      const float4 a = *(const float4*)&Wf[(size_t)(i_base + srow) * K + k0 + sseg * 8];
      const float4 b = *(const float4*)&Wf[(size_t)(i_base + srow) * K + k0 + sseg * 8 + 4];
      uint4 p = { pack2bf(a.x, a.y), pack2bf(a.z, a.w), pack2bf(b.x, b.y), pack2bf(b.z, b.w) };
      *(uint4*)&Wt[srow][sseg * 8] = p;
    } else {
      *(uint4*)&Wt[srow][sseg * 8] =
          *(const uint4*)&((const unsigned short*)Wv)[(size_t)(i_base + srow) * K + k0 + sseg * 8];
    }
    if (XFP32) {
      const float* Xf = (const float*)Xv;
      const float4 a = *(const float4*)&Xf[(size_t)(b_base + srow) * K + k0 + sseg * 8];
      const float4 b = *(const float4*)&Xf[(size_t)(b_base + srow) * K + k0 + sseg * 8 + 4];
      uint4 p = { pack2bf(a.x, a.y), pack2bf(a.z, a.w), pack2bf(b.x, b.y), pack2bf(b.z, b.w) };
      *(uint4*)&Xt[srow][sseg * 8] = p;
    } else {
      *(uint4*)&Xt[srow][sseg * 8] =
          *(const uint4*)&((const unsigned short*)Xv)[(size_t)(b_base + srow) * K + k0 + sseg * 8];
    }
    __syncthreads();
    bf16x8 a0 = *(const bf16x8*)&Wt[wn * 32 + L15][q * 8];
    bf16x8 a1 = *(const bf16x8*)&Wt[wn * 32 + 16 + L15][q * 8];
    bf16x8 b0 = *(const bf16x8*)&Xt[wb * 32 + L15][q * 8];
    bf16x8 b1 = *(const bf16x8*)&Xt[wb * 32 + 16 + L15][q * 8];
    acc[0][0] = __builtin_amdgcn_mfma_f32_16x16x32_bf16(a0, b0, acc[0][0], 0, 0, 0);
    acc[0][1] = __builtin_amdgcn_mfma_f32_16x16x32_bf16(a0, b1, acc[0][1], 0, 0, 0);
    acc[1][0] = __builtin_amdgcn_mfma_f32_16x16x32_bf16(a1, b0, acc[1][0], 0, 0, 0);
    acc[1][1] = __builtin_amdgcn_mfma_f32_16x16x32_bf16(a1, b1, acc[1][1], 0, 0, 0);
    __syncthreads();
  }

  const int nb0 = i_base + wn * 32;
  const int bc0 = b_base + wb * 32 + L15;
#pragma unroll
  for (int mg = 0; mg < 2; mg++) {
    const int nrow = nb0 + mg * 16 + q * 4;
    const float bi0 = bias[nrow], bi1 = bias[nrow + 1];
    const float bi2 = bias[nrow + 2], bi3 = bias[nrow + 3];
#pragma unroll
    for (int bg = 0; bg < 2; bg++) {
      const int b = bc0 + bg * 16;
      f32x4 A = acc[mg][bg];
      const float a0 = __builtin_amdgcn_rcpf(1.f + __expf(-(A[0] + bi0)));
      const float a1 = __builtin_amdgcn_rcpf(1.f + __expf(-(A[1] + bi1)));
      const float a2 = __builtin_amdgcn_rcpf(1.f + __expf(-(A[2] + bi2)));
      const float a3 = __builtin_amdgcn_rcpf(1.f + __expf(-(A[3] + bi3)));
      const float p0 = 0.5f * (a0 + a1), p1 = 0.5f * (a2 + a3);
      const int pidx = nrow >> 1;  // even
      if (out_bf16) {
        *(unsigned int*)&((unsigned short*)Y)[(size_t)b * Np + pidx] = pack2bf(p0, p1);
      } else {
        *(float2*)&((float*)Y)[(size_t)b * Np + pidx] = make_float2(p0, p1);
      }
    }
  }
}

// ---------- prep: Whh -> fp16, hid-interleaved rows, K-stride 128 ----------
// R19: rows pre-scaled by log2(e) (gate 2 rows by 2*log2(e)) so the LSTM act
// uses v_exp_f32 (2^x) directly with no pre-multiply; kk (tanh's 2x) folded.
// Zero pad k in [100,128) is load-bearing: the 4th MFMA k-tile multiplies a
// broadcast B3 fragment whose k>=104 slots are garbage -- A must be 0 there.
#define LOG2E 1.44269504f
#define TWOL2E 2.88539008f
__global__ __launch_bounds__(256) void prep_whh(
    const float* __restrict__ Whh, const float* __restrict__ b3,
    _Float16* __restrict__ P) {
  const int idx = blockIdx.x * 256 + threadIdx.x;  // (row, chunk-of-8)
  if (idx >= 400 * 16) return;
  const int row = idx >> 4, ch = idx & 15;
  const int hid = row >> 2, gate = row & 3;
  const int src = gate * 100 + hid;
  const float s = (gate == 2) ? TWOL2E : LOG2E;
  f16x8 v;
#pragma unroll
  for (int j = 0; j < 8; j++) {
    const int k = ch * 8 + j;
    float f = 0.f;
    if (k < 100) f = Whh[(size_t)src * 100 + k] * s;
    v[j] = (_Float16)f;
  }
  *(f16x8*)&P[(size_t)row * 128 + ch * 8] = v;
}

// ---------- MFMA LSTM (R20 == R19 + exp2 builtin fix) ----------
// R17/R18 post-mortem: dense 16-batch blocks are a wall-time regression --
// with 256 blocks == 256 CUs the R0 structure already runs every batch in
// parallel, and wall = 256 x step critical path. Trans issue is
// exec-mask-independent, so dense cols don't reduce per-CU trans either.
// R19/R20 reverts to the 138.6us structure and shortens the serial chain:
//  (1) k-tail [96,100) folded into a 4th MFMA k-tile: B3 is read at quad0's
//      address by ALL quads (pure LDS broadcast); quads 1-3 receive h[96:104)
//      at k-slots >= 104 where A == 0 (prep zero-pad) -> product unchanged.
//      Deletes the ht b64 read + 4 serial FMAs from the act chain.
//  (2) bias enters as the MFMA C-init (off-chain) instead of zs+bz.
//  (3) exp2-prescaled weights: each sigmoid site is one v_exp_f32
//      (__builtin_amdgcn_exp2f -- __exp2f does not exist in HIP device code).
#define TSTEPS 256

__device__ __forceinline__ float qb0(float x) {
  return __builtin_bit_cast(float, __builtin_amdgcn_mov_dpp(__builtin_bit_cast(int, x), 0x00, 0xf, 0xf, true));
}
__device__ __forceinline__ float qb1(float x) {
  return __builtin_bit_cast(float, __builtin_amdgcn_mov_dpp(__builtin_bit_cast(int, x), 0x55, 0xf, 0xf, true));
}
__device__ __forceinline__ float qb2(float x) {
  return __builtin_bit_cast(float, __builtin_amdgcn_mov_dpp(__builtin_bit_cast(int, x), 0xAA, 0xf, 0xf, true));
}
__device__ __forceinline__ float qb3(float x) {
  return __builtin_bit_cast(float, __builtin_amdgcn_mov_dpp(__builtin_bit_cast(int, x), 0xFF, 0xf, 0xf, true));
}

__global__ __launch_bounds__(512, 2) void lstm_mfma(
    const float* __restrict__ X, const _Float16* __restrict__ P,
    const float* __restrict__ Wih, const float* __restrict__ b3,
    const float* __restrict__ Wout, const float* __restrict__ bout,
    float* __restrict__ out) {
  const int bat = blockIdx.x;
  const int t = threadIdx.x;
  const int w = t >> 6, lane = t & 63;
  const int quad = lane >> 4, c = lane & 15;
  const int TB = (w == 7) ? 21 : w * 3;   // tile base
  const int NT = (w == 7) ? 4 : 3;        // tiles this wave activates

  __shared__ __align__(16) _Float16 hbuf[2][128];
  __shared__ float xrow[TSTEPS];
  __shared__ float red[128];

  for (int i = t; i < TSTEPS; i += 512) xrow[i] = X[(size_t)bat * TSTEPS + i];
  if (t < 128) { hbuf[0][t] = (_Float16)0.f; hbuf[1][t] = (_Float16)0.f; }

  // 16 A-fragments (4 tiles x 4 k-tiles). k-tile 3 rows are zero for
  // k >= 104 (quads 1-3 read pure zeros -> broadcast-B3 trick is exact).
#define LDA(J, KT) const f16x8 A##J##KT = \
    *(const f16x8*)&P[(size_t)((TB + J) * 16 + c) * 128 + (KT) * 32 + quad * 8];
  LDA(0,0) LDA(0,1) LDA(0,2) LDA(0,3)
  LDA(1,0) LDA(1,1) LDA(1,2) LDA(1,3)
  LDA(2,0) LDA(2,1) LDA(2,2) LDA(2,3)
  LDA(3,0) LDA(3,1) LDA(3,2) LDA(3,3)
#undef LDA

  // bias as MFMA C-init: b3v[J][r] = scaled bias of gate r, hid 4*(TB+J)+quad
  f32x4 b3v[4];
#pragma unroll
  for (int J = 0; J < 4; J++) {
    if (J < NT) {
      const int hid = 4 * (TB + J) + quad;
#pragma unroll
      for (int r = 0; r < 4; r++)
        b3v[J][r] = b3[r * 100 + hid] * ((r == 2) ? TWOL2E : LOG2E);
    } else {
      b3v[J] = (f32x4){0.f, 0.f, 0.f, 0.f};
    }
  }

  // activation role: lane handles gate g of hid 4*(TB+J)+quad
  const bool act = (c < 4 * NT);
  const int J = c >> 2, g = c & 3;
  const int myhid = 4 * (TB + (act ? J : 0)) + quad;  // < 100
  const int grow = g * 100 + myhid;                   // row in original gate layout
  const float u_ = Wih[grow] * ((g == 2) ? TWOL2E : LOG2E);
  const float mm = (g == 2) ? 2.f : 1.f;
  const float dd = (g == 2) ? -1.f : 0.f;
  float cst = 0.f;
  __syncthreads();

#define SIG2(zz) __builtin_amdgcn_rcpf(1.f + __builtin_amdgcn_exp2f(-(zz)))
#define STEPB(HC, HN, XT)                                                      \
  {                                                                            \
    const _Float16* hc = (HC);                                                 \
    const f16x8 B0 = *(const f16x8*)&hc[0 * 32 + quad * 8];                    \
    const f16x8 B1 = *(const f16x8*)&hc[1 * 32 + quad * 8];                    \
    const f16x8 B2 = *(const f16x8*)&hc[2 * 32 + quad * 8];                    \
    const f16x8 B3 = *(const f16x8*)&hc[96]; /* quad0 addr: LDS broadcast */   \
    f32x4 z0, z1, z2, z3 = {0.f,0.f,0.f,0.f};                                  \
    { f32x4 za = b3v[0], zb = {0.f,0.f,0.f,0.f};                               \
      za = __builtin_amdgcn_mfma_f32_16x16x32_f16(A00, B0, za, 0, 0, 0);       \
      zb = __builtin_amdgcn_mfma_f32_16x16x32_f16(A01, B1, zb, 0, 0, 0);       \
      za = __builtin_amdgcn_mfma_f32_16x16x32_f16(A02, B2, za, 0, 0, 0);       \
      zb = __builtin_amdgcn_mfma_f32_16x16x32_f16(A03, B3, zb, 0, 0, 0);       \
      z0 = za + zb; }                                                          \
    { f32x4 za = b3v[1], zb = {0.f,0.f,0.f,0.f};                               \
      za = __builtin_amdgcn_mfma_f32_16x16x32_f16(A10, B0, za, 0, 0, 0);       \
      zb = __builtin_amdgcn_mfma_f32_16x16x32_f16(A11, B1, zb, 0, 0, 0);       \
      za = __builtin_amdgcn_mfma_f32_16x16x32_f16(A12, B2, za, 0, 0, 0);       \
      zb = __builtin_amdgcn_mfma_f32_16x16x32_f16(A13, B3, zb, 0, 0, 0);       \
      z1 = za + zb; }                                                          \
    { f32x4 za = b3v[2], zb = {0.f,0.f,0.f,0.f};                               \
      za = __builtin_amdgcn_mfma_f32_16x16x32_f16(A20, B0, za, 0, 0, 0);       \
      zb = __builtin_amdgcn_mfma_f32_16x16x32_f16(A21, B1, zb, 0, 0, 0);       \
      za = __builtin_amdgcn_mfma_f32_16x16x32_f16(A22, B2, za, 0, 0, 0);       \
      zb = __builtin_amdgcn_mfma_f32_16x16x32_f16(A23, B3, zb, 0, 0, 0);       \
      z2 = za + zb; }                                                          \
    if (w == 7) {                                                              \
      f32x4 za = b3v[3], zb = {0.f,0.f,0.f,0.f};                               \
      za = __builtin_amdgcn_mfma_f32_16x16x32_f16(A30, B0, za, 0, 0, 0);       \
      zb = __builtin_amdgcn_mfma_f32_16x16x32_f16(A31, B1, zb, 0, 0, 0);       \
      za = __builtin_amdgcn_mfma_f32_16x16x32_f16(A32, B2, za, 0, 0, 0);       \
      zb = __builtin_amdgcn_mfma_f32_16x16x32_f16(A33, B3, zb, 0, 0, 0);       \
      z3 = za + zb; }                                                          \
    if (act) {                                                                 \
      const f32x4 zt = (J == 0) ? z0 : (J == 1) ? z1 : (J == 2) ? z2 : z3;     \
      float zs = (g == 0) ? zt[0] : (g == 1) ? zt[1] : (g == 2) ? zt[2] : zt[3];\
      zs = fmaf(u_, (XT), zs);                                                 \
      const float a = mm * SIG2(zs) + dd;                                      \
      const float ai = qb0(a), af = qb1(a), ag = qb2(a), ao = qb3(a);          \
      cst = fmaf(af, cst, ai * ag);                                            \
      const float th = 2.f * SIG2(TWOL2E * cst) - 1.f;                         \
      if (g == 0) (HN)[myhid] = (_Float16)(ao * th);                           \
    }                                                                          \
    __syncthreads();                                                           \
  }

  for (int step = 0; step < TSTEPS; step += 2) {
    STEPB(hbuf[0], hbuf[1], xrow[step]);
    STEPB(hbuf[1], hbuf[0], xrow[step + 1]);
  }
#undef STEPB
#undef SIG2

  // out[bat] = dot(h_final, Wout) + bout; final h in hbuf[0]
  if (t < 128) {
    float a = 0.f;
    if (t < 100) a = (float)hbuf[0][t] * Wout[t];
    red[t] = a;
  }
  __syncthreads();
  if (t == 0) {
    float s = 0.f;
#pragma unroll
    for (int k = 0; k < 128; k++) s += red[k];
    out[bat] = s + bout[0];
  }
}

// ---------- launch ----------
extern "C" void kernel_launch(void* const* d_in, const int* in_sizes, int n_in,
                              void* d_out, int out_size, void* d_ws, size_t ws_size,
                              hipStream_t stream) {
  const float* x    = (const float*)d_in[0];   // (256,1024)
  const float* W1L  = (const float*)d_in[3];   // (1024,1024)
  const float* b1L  = (const float*)d_in[4];
  const float* W2L  = (const float*)d_in[7];   // (512,512)
  const float* b2L  = (const float*)d_in[8];
  const float* Wih3 = (const float*)d_in[15];  // (400,1)
  const float* Whh3 = (const float*)d_in[16];  // (400,100)
  const float* b3   = (const float*)d_in[17];  // (400,)
  const float* Wout = (const float*)d_in[18];  // (1,100)
  const float* bout = (const float*)d_in[19];  // (1,)
  float* out = (float*)d_out;                  // (256,)

  unsigned short* xl1b = (unsigned short*)d_ws;        // 256x512 bf16
  float* xl2 = (float*)(xl1b + (size_t)256 * 512);     // 256x256 f32
  _Float16* P = (_Float16*)(xl2 + (size_t)256 * 256);  // 400x128 fp16

  prep_whh<<<25, 256, 0, stream>>>(Whh3, b3, P);
  gemm_mfma_sig_pool<1, 1><<<dim3(16, 4), 256, 0, stream>>>(W1L, b1L, x, xl1b, 1024, 512, 1);
  gemm_mfma_sig_pool<1, 0><<<dim3(8, 4), 256, 0, stream>>>(W2L, b2L, xl1b, xl2, 512, 256, 0);
  lstm_mfma<<<256, 512, 0, stream>>>(xl2, P, Wih3, b3, Wout, bout, out);
}

// Round 5
// 241.622 us; speedup vs baseline: 1.4308x; 1.1241x over previous
//
#include <hip/hip_runtime.h>
#include <math.h>

typedef __bf16 bf16x8 __attribute__((ext_vector_type(8)));
typedef _Float16 f16x8 __attribute__((ext_vector_type(8)));
typedef _Float16 f16x4 __attribute__((ext_vector_type(4)));
typedef float f32x4 __attribute__((ext_vector_type(4)));

__device__ __forceinline__ unsigned short f2bf(float f) {
  unsigned int u = __builtin_bit_cast(unsigned int, f);
  u += 0x7fffu + ((u >> 16) & 1u);
  return (unsigned short)(u >> 16);
}
__device__ __forceinline__ unsigned int pack2bf(float a, float b) {
  return (unsigned int)f2bf(a) | ((unsigned int)f2bf(b) << 16);
}

// ---------- bf16 MFMA GEMM + sigmoid + avgpool2 ----------
// R21: BK 32->64 (half the barriers) + register double-buffer prefetch.
// The old loop was fully serial per k-iter: gload -> convert -> barrier ->
// ds_read -> MFMA -> barrier (no overlap, 1 wave/SIMD). Now the next 64-K
// slab's global loads are issued before staging the current one, so load
// latency hides under stage+MFMA+barrier (compiler emits counted vmcnt).
// Pad 72 elems (144B = 36 banks) keeps ds_read/store aliasing <= 2-way (free).
#define GK_PAD2 72
template <int WFP32, int XFP32>
__global__ __launch_bounds__(256) void gemm_mfma_sig_pool(
    const void* __restrict__ Wv, const float* __restrict__ bias,
    const void* __restrict__ Xv, void* __restrict__ Y,
    int K, int Np, int out_bf16) {
  __shared__ unsigned short Wt[64][GK_PAD2];
  __shared__ unsigned short Xt[64][GK_PAD2];
  const int tid = threadIdx.x;
  const int i_base = blockIdx.x * 64;
  const int b_base = blockIdx.y * 64;
  const int srow = tid >> 2, sseg = tid & 3;
  const int wv = tid >> 6, lane = tid & 63;
  const int wn = wv & 1, wb = wv >> 1;
  const int L15 = lane & 15, q = lane >> 4;

  const float* Wf = (const float*)Wv;
  const float* Xf = (const float*)Xv;
  const unsigned short* Wh = (const unsigned short*)Wv;
  const unsigned short* Xh = (const unsigned short*)Xv;

  // two register slots per side (ping-pong, statically indexed)
  float4 wf[2][4], xf[2][4];
  uint4 wh[2][2], xh[2][2];

#define LOADW(S, KO)                                                          \
  do {                                                                        \
    if (WFP32) {                                                              \
      _Pragma("unroll") for (int j = 0; j < 4; j++)                           \
          wf[S][j] = *(const float4*)&Wf[(size_t)(i_base + srow) * K + (KO) + \
                                         sseg * 16 + 4 * j];                  \
    } else {                                                                  \
      _Pragma("unroll") for (int j = 0; j < 2; j++)                           \
          wh[S][j] = *(const uint4*)&Wh[(size_t)(i_base + srow) * K + (KO) +  \
                                        sseg * 16 + 8 * j];                   \
    }                                                                         \
  } while (0)

#define LOADX(S, KO)                                                          \
  do {                                                                        \
    if (XFP32) {                                                              \
      _Pragma("unroll") for (int j = 0; j < 4; j++)                           \
          xf[S][j] = *(const float4*)&Xf[(size_t)(b_base + srow) * K + (KO) + \
                                         sseg * 16 + 4 * j];                  \
    } else {                                                                  \
      _Pragma("unroll") for (int j = 0; j < 2; j++)                           \
          xh[S][j] = *(const uint4*)&Xh[(size_t)(b_base + srow) * K + (KO) +  \
                                        sseg * 16 + 8 * j];                   \
    }                                                                         \
  } while (0)

#define STAGEW(S)                                                             \
  do {                                                                        \
    if (WFP32) {                                                              \
      uint4 p0 = {pack2bf(wf[S][0].x, wf[S][0].y),                            \
                  pack2bf(wf[S][0].z, wf[S][0].w),                            \
                  pack2bf(wf[S][1].x, wf[S][1].y),                            \
                  pack2bf(wf[S][1].z, wf[S][1].w)};                           \
      uint4 p1 = {pack2bf(wf[S][2].x, wf[S][2].y),                            \
                  pack2bf(wf[S][2].z, wf[S][2].w),                            \
                  pack2bf(wf[S][3].x, wf[S][3].y),                            \
                  pack2bf(wf[S][3].z, wf[S][3].w)};                           \
      *(uint4*)&Wt[srow][sseg * 16] = p0;                                     \
      *(uint4*)&Wt[srow][sseg * 16 + 8] = p1;                                 \
    } else {                                                                  \
      *(uint4*)&Wt[srow][sseg * 16] = wh[S][0];                               \
      *(uint4*)&Wt[srow][sseg * 16 + 8] = wh[S][1];                           \
    }                                                                         \
  } while (0)

#define STAGEX(S)                                                             \
  do {                                                                        \
    if (XFP32) {                                                              \
      uint4 p0 = {pack2bf(xf[S][0].x, xf[S][0].y),                            \
                  pack2bf(xf[S][0].z, xf[S][0].w),                            \
                  pack2bf(xf[S][1].x, xf[S][1].y),                            \
                  pack2bf(xf[S][1].z, xf[S][1].w)};                           \
      uint4 p1 = {pack2bf(xf[S][2].x, xf[S][2].y),                            \
                  pack2bf(xf[S][2].z, xf[S][2].w),                            \
                  pack2bf(xf[S][3].x, xf[S][3].y),                            \
                  pack2bf(xf[S][3].z, xf[S][3].w)};                           \
      *(uint4*)&Xt[srow][sseg * 16] = p0;                                     \
      *(uint4*)&Xt[srow][sseg * 16 + 8] = p1;                                 \
    } else {                                                                  \
      *(uint4*)&Xt[srow][sseg * 16] = xh[S][0];                               \
      *(uint4*)&Xt[srow][sseg * 16 + 8] = xh[S][1];                           \
    }                                                                         \
  } while (0)

#define DOMFMA                                                                \
  do {                                                                        \
    _Pragma("unroll") for (int kt = 0; kt < 2; kt++) {                        \
      bf16x8 a0 = *(const bf16x8*)&Wt[wn * 32 + L15][kt * 32 + q * 8];        \
      bf16x8 a1 = *(const bf16x8*)&Wt[wn * 32 + 16 + L15][kt * 32 + q * 8];   \
      bf16x8 b0 = *(const bf16x8*)&Xt[wb * 32 + L15][kt * 32 + q * 8];        \
      bf16x8 b1 = *(const bf16x8*)&Xt[wb * 32 + 16 + L15][kt * 32 + q * 8];   \
      acc[0][0] = __builtin_amdgcn_mfma_f32_16x16x32_bf16(a0, b0, acc[0][0], 0, 0, 0); \
      acc[0][1] = __builtin_amdgcn_mfma_f32_16x16x32_bf16(a0, b1, acc[0][1], 0, 0, 0); \
      acc[1][0] = __builtin_amdgcn_mfma_f32_16x16x32_bf16(a1, b0, acc[1][0], 0, 0, 0); \
      acc[1][1] = __builtin_amdgcn_mfma_f32_16x16x32_bf16(a1, b1, acc[1][1], 0, 0, 0); \
    }                                                                         \
  } while (0)

  f32x4 acc[2][2] = {};
  LOADW(0, 0);
  LOADX(0, 0);
  for (int k0 = 0; k0 < K; k0 += 128) {
    LOADW(1, k0 + 64);  // k0+64 < K always (K multiple of 128)
    LOADX(1, k0 + 64);
    STAGEW(0);
    STAGEX(0);
    __syncthreads();
    DOMFMA;
    __syncthreads();
    if (k0 + 128 < K) {
      LOADW(0, k0 + 128);
      LOADX(0, k0 + 128);
    }
    STAGEW(1);
    STAGEX(1);
    __syncthreads();
    DOMFMA;
    __syncthreads();
  }
#undef LOADW
#undef LOADX
#undef STAGEW
#undef STAGEX
#undef DOMFMA

  const int nb0 = i_base + wn * 32;
  const int bc0 = b_base + wb * 32 + L15;
#pragma unroll
  for (int mg = 0; mg < 2; mg++) {
    const int nrow = nb0 + mg * 16 + q * 4;
    const float bi0 = bias[nrow], bi1 = bias[nrow + 1];
    const float bi2 = bias[nrow + 2], bi3 = bias[nrow + 3];
#pragma unroll
    for (int bg = 0; bg < 2; bg++) {
      const int b = bc0 + bg * 16;
      f32x4 A = acc[mg][bg];
      const float a0 = __builtin_amdgcn_rcpf(1.f + __expf(-(A[0] + bi0)));
      const float a1 = __builtin_amdgcn_rcpf(1.f + __expf(-(A[1] + bi1)));
      const float a2 = __builtin_amdgcn_rcpf(1.f + __expf(-(A[2] + bi2)));
      const float a3 = __builtin_amdgcn_rcpf(1.f + __expf(-(A[3] + bi3)));
      const float p0 = 0.5f * (a0 + a1), p1 = 0.5f * (a2 + a3);
      const int pidx = nrow >> 1;  // even
      if (out_bf16) {
        *(unsigned int*)&((unsigned short*)Y)[(size_t)b * Np + pidx] = pack2bf(p0, p1);
      } else {
        *(float2*)&((float*)Y)[(size_t)b * Np + pidx] = make_float2(p0, p1);
      }
    }
  }
}

// ---------- prep: Whh -> fp16, hid-interleaved rows, K-stride 128 ----------
// Perm row 4*hid+gate = Whh[gate*100+hid][0:100]. Rows pre-scaled by log2(e)
// (gate-2 rows by 2*log2(e)) so every LSTM sigmoid site is a single
// v_exp_f32 (2^x) with no pre-multiply. Only k<96 feeds MFMA; tail in fp32.
#define LOG2E 1.44269504f
#define TWOL2E 2.88539008f
__global__ __launch_bounds__(256) void prep_whh(
    const float* __restrict__ Whh, const float* __restrict__ b3,
    _Float16* __restrict__ P) {
  const int idx = blockIdx.x * 256 + threadIdx.x;  // (row, chunk-of-8)
  if (idx >= 400 * 16) return;
  const int row = idx >> 4, ch = idx & 15;
  const int hid = row >> 2, gate = row & 3;
  const int src = gate * 100 + hid;
  const float s = (gate == 2) ? TWOL2E : LOG2E;
  f16x8 v;
#pragma unroll
  for (int j = 0; j < 8; j++) {
    const int k = ch * 8 + j;
    float f = 0.f;
    if (k < 100) f = Whh[(size_t)src * 100 + k] * s;
    v[j] = (_Float16)f;
  }
  *(f16x8*)&P[(size_t)row * 128 + ch * 8] = v;
}

// ---------- MFMA LSTM (R21 = exact R16/138.6us structure + exp2 prescale) ----
// R20 post-mortem: folding the fp32 tail into a 4th MFMA k-tile REGRESSED
// (138.6 -> 145.4): the tail was overlapped, the 4 extra MFMAs were pure
// added issue. Revert to the proven 3-ktile + fp32-tail structure. Only
// retained trim: P/wt/u_/bz pre-scaled by log2e (2log2e for g-gate) so each
// sigmoid is one v_exp_f32 -- no kk multiply, no other chain change.
#define TSTEPS 256

__device__ __forceinline__ float qb0(float x) {
  return __builtin_bit_cast(float, __builtin_amdgcn_mov_dpp(__builtin_bit_cast(int, x), 0x00, 0xf, 0xf, true));
}
__device__ __forceinline__ float qb1(float x) {
  return __builtin_bit_cast(float, __builtin_amdgcn_mov_dpp(__builtin_bit_cast(int, x), 0x55, 0xf, 0xf, true));
}
__device__ __forceinline__ float qb2(float x) {
  return __builtin_bit_cast(float, __builtin_amdgcn_mov_dpp(__builtin_bit_cast(int, x), 0xAA, 0xf, 0xf, true));
}
__device__ __forceinline__ float qb3(float x) {
  return __builtin_bit_cast(float, __builtin_amdgcn_mov_dpp(__builtin_bit_cast(int, x), 0xFF, 0xf, 0xf, true));
}

__global__ __launch_bounds__(512, 2) void lstm_mfma(
    const float* __restrict__ X, const _Float16* __restrict__ P,
    const float* __restrict__ Whh, const float* __restrict__ Wih,
    const float* __restrict__ b3, const float* __restrict__ Wout,
    const float* __restrict__ bout, float* __restrict__ out) {
  const int bat = blockIdx.x;
  const int t = threadIdx.x;
  const int w = t >> 6, lane = t & 63;
  const int quad = lane >> 4, c = lane & 15;
  const int TB = (w == 7) ? 21 : w * 3;   // tile base
  const int NT = (w == 7) ? 4 : 3;        // tiles this wave activates

  __shared__ __align__(16) _Float16 hbuf[2][128];
  __shared__ float xrow[TSTEPS];
  __shared__ float red[128];

  for (int i = t; i < TSTEPS; i += 512) xrow[i] = X[(size_t)bat * TSTEPS + i];
  if (t < 128) { hbuf[0][t] = (_Float16)0.f; hbuf[1][t] = (_Float16)0.f; }

  // 12 A-fragments (tiles TB..TB+3 all valid rows <= 24; tile 3 used only by w==7)
#define LDA(J, KT) const f16x8 A##J##KT = \
    *(const f16x8*)&P[(size_t)((TB + J) * 16 + c) * 128 + (KT) * 32 + quad * 8];
  LDA(0,0) LDA(0,1) LDA(0,2)
  LDA(1,0) LDA(1,1) LDA(1,2)
  LDA(2,0) LDA(2,1) LDA(2,2)
  LDA(3,0) LDA(3,1) LDA(3,2)
#undef LDA

  // activation role: lane handles gate g of hid 4*(TB+J)+quad
  const bool act = (c < 4 * NT);
  const int J = c >> 2, g = c & 3;
  const int myhid = 4 * (TB + (act ? J : 0)) + quad;  // < 100
  const int grow = g * 100 + myhid;                   // row in original gate layout
  const float sc = (g == 2) ? TWOL2E : LOG2E;         // exp2 prescale
  const float u_ = Wih[grow] * sc;
  const float bz = b3[grow] * sc;
  const float4 wt0 = *(const float4*)&Whh[(size_t)grow * 100 + 96];  // k tail 96..99
  const float4 wt = make_float4(wt0.x * sc, wt0.y * sc, wt0.z * sc, wt0.w * sc);
  const float mm = (g == 2) ? 2.f : 1.f;   // g-gate is tanh = 2*sig(2z)-1
  const float dd = (g == 2) ? -1.f : 0.f;
  float cst = 0.f;
  __syncthreads();

#define SIG2(zz) __builtin_amdgcn_rcpf(1.f + __builtin_amdgcn_exp2f(-(zz)))
#define STEPB(HC, HN, XT)                                                      \
  {                                                                            \
    const _Float16* hc = (HC);                                                 \
    const f16x8 B0 = *(const f16x8*)&hc[0 * 32 + quad * 8];                    \
    const f16x8 B1 = *(const f16x8*)&hc[1 * 32 + quad * 8];                    \
    const f16x8 B2 = *(const f16x8*)&hc[2 * 32 + quad * 8];                    \
    f32x4 z0 = {0.f,0.f,0.f,0.f}, z1 = z0, z2 = z0, z3 = z0;                   \
    { f32x4 za = z0, zb = z0;                                                  \
      za = __builtin_amdgcn_mfma_f32_16x16x32_f16(A00, B0, za, 0, 0, 0);       \
      zb = __builtin_amdgcn_mfma_f32_16x16x32_f16(A01, B1, zb, 0, 0, 0);       \
      za = __builtin_amdgcn_mfma_f32_16x16x32_f16(A02, B2, za, 0, 0, 0);       \
      z0 = za + zb; }                                                          \
    { f32x4 za = {0.f,0.f,0.f,0.f}, zb = za;                                   \
      za = __builtin_amdgcn_mfma_f32_16x16x32_f16(A10, B0, za, 0, 0, 0);       \
      zb = __builtin_amdgcn_mfma_f32_16x16x32_f16(A11, B1, zb, 0, 0, 0);       \
      za = __builtin_amdgcn_mfma_f32_16x16x32_f16(A12, B2, za, 0, 0, 0);       \
      z1 = za + zb; }                                                          \
    { f32x4 za = {0.f,0.f,0.f,0.f}, zb = za;                                   \
      za = __builtin_amdgcn_mfma_f32_16x16x32_f16(A20, B0, za, 0, 0, 0);       \
      zb = __builtin_amdgcn_mfma_f32_16x16x32_f16(A21, B1, zb, 0, 0, 0);       \
      za = __builtin_amdgcn_mfma_f32_16x16x32_f16(A22, B2, za, 0, 0, 0);       \
      z2 = za + zb; }                                                          \
    if (w == 7) {                                                              \
      f32x4 za = {0.f,0.f,0.f,0.f}, zb = za;                                   \
      za = __builtin_amdgcn_mfma_f32_16x16x32_f16(A30, B0, za, 0, 0, 0);       \
      zb = __builtin_amdgcn_mfma_f32_16x16x32_f16(A31, B1, zb, 0, 0, 0);       \
      za = __builtin_amdgcn_mfma_f32_16x16x32_f16(A32, B2, za, 0, 0, 0);       \
      z3 = za + zb; }                                                          \
    if (act) {                                                                 \
      const f32x4 zt = (J == 0) ? z0 : (J == 1) ? z1 : (J == 2) ? z2 : z3;     \
      float zs = (g == 0) ? zt[0] : (g == 1) ? zt[1] : (g == 2) ? zt[2] : zt[3];\
      const f16x4 ht = *(const f16x4*)&hc[96];                                 \
      zs = fmaf(wt.x, (float)ht[0], zs);                                       \
      zs = fmaf(wt.y, (float)ht[1], zs);                                       \
      zs = fmaf(wt.z, (float)ht[2], zs);                                       \
      zs = fmaf(wt.w, (float)ht[3], zs);                                       \
      zs = fmaf(u_, (XT), zs + bz);                                            \
      const float a = mm * SIG2(zs) + dd;                                      \
      const float ai = qb0(a), af = qb1(a), ag = qb2(a), ao = qb3(a);          \
      cst = fmaf(af, cst, ai * ag);                                            \
      const float th = 2.f * SIG2(TWOL2E * cst) - 1.f;                         \
      if (g == 0) (HN)[myhid] = (_Float16)(ao * th);                           \
    }                                                                          \
    __syncthreads();                                                           \
  }

  for (int step = 0; step < TSTEPS; step += 2) {
    STEPB(hbuf[0], hbuf[1], xrow[step]);
    STEPB(hbuf[1], hbuf[0], xrow[step + 1]);
  }
#undef STEPB
#undef SIG2

  // out[bat] = dot(h_final, Wout) + bout; final h in hbuf[0]
  if (t < 128) {
    float a = 0.f;
    if (t < 100) a = (float)hbuf[0][t] * Wout[t];
    red[t] = a;
  }
  __syncthreads();
  if (t == 0) {
    float s = 0.f;
#pragma unroll
    for (int k = 0; k < 128; k++) s += red[k];
    out[bat] = s + bout[0];
  }
}

// ---------- launch ----------
extern "C" void kernel_launch(void* const* d_in, const int* in_sizes, int n_in,
                              void* d_out, int out_size, void* d_ws, size_t ws_size,
                              hipStream_t stream) {
  const float* x    = (const float*)d_in[0];   // (256,1024)
  const float* W1L  = (const float*)d_in[3];   // (1024,1024)
  const float* b1L  = (const float*)d_in[4];
  const float* W2L  = (const float*)d_in[7];   // (512,512)
  const float* b2L  = (const float*)d_in[8];
  const float* Wih3 = (const float*)d_in[15];  // (400,1)
  const float* Whh3 = (const float*)d_in[16];  // (400,100)
  const float* b3   = (const float*)d_in[17];  // (400,)
  const float* Wout = (const float*)d_in[18];  // (1,100)
  const float* bout = (const float*)d_in[19];  // (1,)
  float* out = (float*)d_out;                  // (256,)

  unsigned short* xl1b = (unsigned short*)d_ws;        // 256x512 bf16
  float* xl2 = (float*)(xl1b + (size_t)256 * 512);     // 256x256 f32
  _Float16* P = (_Float16*)(xl2 + (size_t)256 * 256);  // 400x128 fp16

  prep_whh<<<25, 256, 0, stream>>>(Whh3, b3, P);
  gemm_mfma_sig_pool<1, 1><<<dim3(16, 4), 256, 0, stream>>>(W1L, b1L, x, xl1b, 1024, 512, 1);
  gemm_mfma_sig_pool<1, 0><<<dim3(8, 4), 256, 0, stream>>>(W2L, b2L, xl1b, xl2, 512, 256, 0);
  lstm_mfma<<<256, 512, 0, stream>>>(xl2, P, Whh3, Wih3, b3, Wout, bout, out);
}

// Round 6
// 231.127 us; speedup vs baseline: 1.4958x; 1.0454x over previous
//
#include <hip/hip_runtime.h>
#include <math.h>

typedef __bf16 bf16x8 __attribute__((ext_vector_type(8)));
typedef _Float16 f16x8 __attribute__((ext_vector_type(8)));
typedef _Float16 f16x4 __attribute__((ext_vector_type(4)));
typedef float f32x4 __attribute__((ext_vector_type(4)));

__device__ __forceinline__ unsigned short f2bf(float f) {
  unsigned int u = __builtin_bit_cast(unsigned int, f);
  u += 0x7fffu + ((u >> 16) & 1u);
  return (unsigned short)(u >> 16);
}
__device__ __forceinline__ unsigned int pack2bf(float a, float b) {
  return (unsigned int)f2bf(a) | ((unsigned int)f2bf(b) << 16);
}

// ---------- bf16 MFMA GEMM + sigmoid + avgpool2 ----------
// R22: tile 64 rows x 16 batches (was 64x64) -> grid.y 4->16: gemm1 256
// blocks, gemm2 128 blocks (was 64/32 = quarter/eighth of the chip). The
// GEMMs were latency/BW-bound on too few CUs (~25 GB/s per-CU HBM); W-panel
// refetch across y-blocks is L2/L3-served (W1L=4MB fits L2). Keeps R21's
// BK=64 register double-buffer prefetch. 4 waves row-split (16 rows each),
// one f32x4 acc per wave.
#define GK_PAD2 72
template <int WFP32, int XFP32>
__global__ __launch_bounds__(256) void gemm_mfma_sig_pool(
    const void* __restrict__ Wv, const float* __restrict__ bias,
    const void* __restrict__ Xv, void* __restrict__ Y,
    int K, int Np, int out_bf16) {
  __shared__ unsigned short Wt[64][GK_PAD2];
  __shared__ unsigned short Xt[16][GK_PAD2];
  const int tid = threadIdx.x;
  const int i_base = blockIdx.x * 64;
  const int b_base = blockIdx.y * 16;
  const int srow = tid >> 2, sseg = tid & 3;   // W stage: 64 rows x 4 segs of 16
  const int xr = tid >> 4, xs = tid & 15;      // X stage: 16 rows x 16 segs of 4
  const int wv = tid >> 6, lane = tid & 63;
  const int L15 = lane & 15, q = lane >> 4;

  const float* Wf = (const float*)Wv;
  const float* Xf = (const float*)Xv;
  const unsigned short* Wh = (const unsigned short*)Wv;
  const unsigned short* Xh = (const unsigned short*)Xv;

  // two register slots per side (ping-pong, statically indexed)
  float4 wf[2][4];
  uint4 wh[2][2];
  float4 xf[2];
  uint2 xh2[2];

#define LOADW(S, KO)                                                          \
  do {                                                                        \
    if (WFP32) {                                                              \
      _Pragma("unroll") for (int j = 0; j < 4; j++)                           \
          wf[S][j] = *(const float4*)&Wf[(size_t)(i_base + srow) * K + (KO) + \
                                         sseg * 16 + 4 * j];                  \
    } else {                                                                  \
      _Pragma("unroll") for (int j = 0; j < 2; j++)                           \
          wh[S][j] = *(const uint4*)&Wh[(size_t)(i_base + srow) * K + (KO) +  \
                                        sseg * 16 + 8 * j];                   \
    }                                                                         \
  } while (0)

#define LOADX(S, KO)                                                          \
  do {                                                                        \
    if (XFP32) {                                                              \
      xf[S] = *(const float4*)&Xf[(size_t)(b_base + xr) * K + (KO) + xs * 4]; \
    } else {                                                                  \
      xh2[S] = *(const uint2*)&Xh[(size_t)(b_base + xr) * K + (KO) + xs * 4]; \
    }                                                                         \
  } while (0)

#define STAGEW(S)                                                             \
  do {                                                                        \
    if (WFP32) {                                                              \
      uint4 p0 = {pack2bf(wf[S][0].x, wf[S][0].y),                            \
                  pack2bf(wf[S][0].z, wf[S][0].w),                            \
                  pack2bf(wf[S][1].x, wf[S][1].y),                            \
                  pack2bf(wf[S][1].z, wf[S][1].w)};                           \
      uint4 p1 = {pack2bf(wf[S][2].x, wf[S][2].y),                            \
                  pack2bf(wf[S][2].z, wf[S][2].w),                            \
                  pack2bf(wf[S][3].x, wf[S][3].y),                            \
                  pack2bf(wf[S][3].z, wf[S][3].w)};                           \
      *(uint4*)&Wt[srow][sseg * 16] = p0;                                     \
      *(uint4*)&Wt[srow][sseg * 16 + 8] = p1;                                 \
    } else {                                                                  \
      *(uint4*)&Wt[srow][sseg * 16] = wh[S][0];                               \
      *(uint4*)&Wt[srow][sseg * 16 + 8] = wh[S][1];                           \
    }                                                                         \
  } while (0)

#define STAGEX(S)                                                             \
  do {                                                                        \
    if (XFP32) {                                                              \
      uint2 p = {pack2bf(xf[S].x, xf[S].y), pack2bf(xf[S].z, xf[S].w)};       \
      *(uint2*)&Xt[xr][xs * 4] = p;                                           \
    } else {                                                                  \
      *(uint2*)&Xt[xr][xs * 4] = xh2[S];                                      \
    }                                                                         \
  } while (0)

#define DOMFMA                                                                \
  do {                                                                        \
    _Pragma("unroll") for (int kt = 0; kt < 2; kt++) {                        \
      bf16x8 a = *(const bf16x8*)&Wt[wv * 16 + L15][kt * 32 + q * 8];         \
      bf16x8 b = *(const bf16x8*)&Xt[L15][kt * 32 + q * 8];                   \
      acc = __builtin_amdgcn_mfma_f32_16x16x32_bf16(a, b, acc, 0, 0, 0);      \
    }                                                                         \
  } while (0)

  f32x4 acc = {};
  LOADW(0, 0);
  LOADX(0, 0);
  for (int k0 = 0; k0 < K; k0 += 128) {
    LOADW(1, k0 + 64);  // k0+64 < K always (K multiple of 128)
    LOADX(1, k0 + 64);
    STAGEW(0);
    STAGEX(0);
    __syncthreads();
    DOMFMA;
    __syncthreads();
    if (k0 + 128 < K) {
      LOADW(0, k0 + 128);
      LOADX(0, k0 + 128);
    }
    STAGEW(1);
    STAGEX(1);
    __syncthreads();
    DOMFMA;
    __syncthreads();
  }
#undef LOADW
#undef LOADX
#undef STAGEW
#undef STAGEX
#undef DOMFMA

  // epilogue: rows i_base+16*wv+q*4 .. +3, batch col b_base+L15
  {
    const int nrow = i_base + 16 * wv + q * 4;
    const float bi0 = bias[nrow], bi1 = bias[nrow + 1];
    const float bi2 = bias[nrow + 2], bi3 = bias[nrow + 3];
    const int b = b_base + L15;
    const float a0 = __builtin_amdgcn_rcpf(1.f + __expf(-(acc[0] + bi0)));
    const float a1 = __builtin_amdgcn_rcpf(1.f + __expf(-(acc[1] + bi1)));
    const float a2 = __builtin_amdgcn_rcpf(1.f + __expf(-(acc[2] + bi2)));
    const float a3 = __builtin_amdgcn_rcpf(1.f + __expf(-(acc[3] + bi3)));
    const float p0 = 0.5f * (a0 + a1), p1 = 0.5f * (a2 + a3);
    const int pidx = nrow >> 1;  // even
    if (out_bf16) {
      *(unsigned int*)&((unsigned short*)Y)[(size_t)b * Np + pidx] = pack2bf(p0, p1);
    } else {
      *(float2*)&((float*)Y)[(size_t)b * Np + pidx] = make_float2(p0, p1);
    }
  }
}

// ---------- prep: Whh -> fp16, hid-interleaved rows, K-stride 128 ----------
// Perm row 4*hid+gate = Whh[gate*100+hid][0:100]. Rows pre-scaled by log2(e)
// (gate-2 rows by 2*log2(e)) so every LSTM sigmoid site is a single
// v_exp_f32 (2^x) with no pre-multiply. Only k<96 feeds MFMA; tail in fp32.
#define LOG2E 1.44269504f
#define TWOL2E 2.88539008f
__global__ __launch_bounds__(256) void prep_whh(
    const float* __restrict__ Whh, const float* __restrict__ b3,
    _Float16* __restrict__ P) {
  const int idx = blockIdx.x * 256 + threadIdx.x;  // (row, chunk-of-8)
  if (idx >= 400 * 16) return;
  const int row = idx >> 4, ch = idx & 15;
  const int hid = row >> 2, gate = row & 3;
  const int src = gate * 100 + hid;
  const float s = (gate == 2) ? TWOL2E : LOG2E;
  f16x8 v;
#pragma unroll
  for (int j = 0; j < 8; j++) {
    const int k = ch * 8 + j;
    float f = 0.f;
    if (k < 100) f = Whh[(size_t)src * 100 + k] * s;
    v[j] = (_Float16)f;
  }
  *(f16x8*)&P[(size_t)row * 128 + ch * 8] = v;
}

// ---------- MFMA LSTM (byte-identical to R21's measured 134.0us) ----------
// R20 post-mortem: folding the fp32 tail into a 4th MFMA k-tile REGRESSED
// (138.6 -> 145.4): the tail was overlapped, the 4 extra MFMAs were pure
// added issue. Proven 3-ktile + fp32-tail structure + exp2 prescale.
#define TSTEPS 256

__device__ __forceinline__ float qb0(float x) {
  return __builtin_bit_cast(float, __builtin_amdgcn_mov_dpp(__builtin_bit_cast(int, x), 0x00, 0xf, 0xf, true));
}
__device__ __forceinline__ float qb1(float x) {
  return __builtin_bit_cast(float, __builtin_amdgcn_mov_dpp(__builtin_bit_cast(int, x), 0x55, 0xf, 0xf, true));
}
__device__ __forceinline__ float qb2(float x) {
  return __builtin_bit_cast(float, __builtin_amdgcn_mov_dpp(__builtin_bit_cast(int, x), 0xAA, 0xf, 0xf, true));
}
__device__ __forceinline__ float qb3(float x) {
  return __builtin_bit_cast(float, __builtin_amdgcn_mov_dpp(__builtin_bit_cast(int, x), 0xFF, 0xf, 0xf, true));
}

__global__ __launch_bounds__(512, 2) void lstm_mfma(
    const float* __restrict__ X, const _Float16* __restrict__ P,
    const float* __restrict__ Whh, const float* __restrict__ Wih,
    const float* __restrict__ b3, const float* __restrict__ Wout,
    const float* __restrict__ bout, float* __restrict__ out) {
  const int bat = blockIdx.x;
  const int t = threadIdx.x;
  const int w = t >> 6, lane = t & 63;
  const int quad = lane >> 4, c = lane & 15;
  const int TB = (w == 7) ? 21 : w * 3;   // tile base
  const int NT = (w == 7) ? 4 : 3;        // tiles this wave activates

  __shared__ __align__(16) _Float16 hbuf[2][128];
  __shared__ float xrow[TSTEPS];
  __shared__ float red[128];

  for (int i = t; i < TSTEPS; i += 512) xrow[i] = X[(size_t)bat * TSTEPS + i];
  if (t < 128) { hbuf[0][t] = (_Float16)0.f; hbuf[1][t] = (_Float16)0.f; }

  // 12 A-fragments (tiles TB..TB+3 all valid rows <= 24; tile 3 used only by w==7)
#define LDA(J, KT) const f16x8 A##J##KT = \
    *(const f16x8*)&P[(size_t)((TB + J) * 16 + c) * 128 + (KT) * 32 + quad * 8];
  LDA(0,0) LDA(0,1) LDA(0,2)
  LDA(1,0) LDA(1,1) LDA(1,2)
  LDA(2,0) LDA(2,1) LDA(2,2)
  LDA(3,0) LDA(3,1) LDA(3,2)
#undef LDA

  // activation role: lane handles gate g of hid 4*(TB+J)+quad
  const bool act = (c < 4 * NT);
  const int J = c >> 2, g = c & 3;
  const int myhid = 4 * (TB + (act ? J : 0)) + quad;  // < 100
  const int grow = g * 100 + myhid;                   // row in original gate layout
  const float sc = (g == 2) ? TWOL2E : LOG2E;         // exp2 prescale
  const float u_ = Wih[grow] * sc;
  const float bz = b3[grow] * sc;
  const float4 wt0 = *(const float4*)&Whh[(size_t)grow * 100 + 96];  // k tail 96..99
  const float4 wt = make_float4(wt0.x * sc, wt0.y * sc, wt0.z * sc, wt0.w * sc);
  const float mm = (g == 2) ? 2.f : 1.f;   // g-gate is tanh = 2*sig(2z)-1
  const float dd = (g == 2) ? -1.f : 0.f;
  float cst = 0.f;
  __syncthreads();

#define SIG2(zz) __builtin_amdgcn_rcpf(1.f + __builtin_amdgcn_exp2f(-(zz)))
#define STEPB(HC, HN, XT)                                                      \
  {                                                                            \
    const _Float16* hc = (HC);                                                 \
    const f16x8 B0 = *(const f16x8*)&hc[0 * 32 + quad * 8];                    \
    const f16x8 B1 = *(const f16x8*)&hc[1 * 32 + quad * 8];                    \
    const f16x8 B2 = *(const f16x8*)&hc[2 * 32 + quad * 8];                    \
    f32x4 z0 = {0.f,0.f,0.f,0.f}, z1 = z0, z2 = z0, z3 = z0;                   \
    { f32x4 za = z0, zb = z0;                                                  \
      za = __builtin_amdgcn_mfma_f32_16x16x32_f16(A00, B0, za, 0, 0, 0);       \
      zb = __builtin_amdgcn_mfma_f32_16x16x32_f16(A01, B1, zb, 0, 0, 0);       \
      za = __builtin_amdgcn_mfma_f32_16x16x32_f16(A02, B2, za, 0, 0, 0);       \
      z0 = za + zb; }                                                          \
    { f32x4 za = {0.f,0.f,0.f,0.f}, zb = za;                                   \
      za = __builtin_amdgcn_mfma_f32_16x16x32_f16(A10, B0, za, 0, 0, 0);       \
      zb = __builtin_amdgcn_mfma_f32_16x16x32_f16(A11, B1, zb, 0, 0, 0);       \
      za = __builtin_amdgcn_mfma_f32_16x16x32_f16(A12, B2, za, 0, 0, 0);       \
      z1 = za + zb; }                                                          \
    { f32x4 za = {0.f,0.f,0.f,0.f}, zb = za;                                   \
      za = __builtin_amdgcn_mfma_f32_16x16x32_f16(A20, B0, za, 0, 0, 0);       \
      zb = __builtin_amdgcn_mfma_f32_16x16x32_f16(A21, B1, zb, 0, 0, 0);       \
      za = __builtin_amdgcn_mfma_f32_16x16x32_f16(A22, B2, za, 0, 0, 0);       \
      z2 = za + zb; }                                                          \
    if (w == 7) {                                                              \
      f32x4 za = {0.f,0.f,0.f,0.f}, zb = za;                                   \
      za = __builtin_amdgcn_mfma_f32_16x16x32_f16(A30, B0, za, 0, 0, 0);       \
      zb = __builtin_amdgcn_mfma_f32_16x16x32_f16(A31, B1, zb, 0, 0, 0);       \
      za = __builtin_amdgcn_mfma_f32_16x16x32_f16(A32, B2, za, 0, 0, 0);       \
      z3 = za + zb; }                                                          \
    if (act) {                                                                 \
      const f32x4 zt = (J == 0) ? z0 : (J == 1) ? z1 : (J == 2) ? z2 : z3;     \
      float zs = (g == 0) ? zt[0] : (g == 1) ? zt[1] : (g == 2) ? zt[2] : zt[3];\
      const f16x4 ht = *(const f16x4*)&hc[96];                                 \
      zs = fmaf(wt.x, (float)ht[0], zs);                                       \
      zs = fmaf(wt.y, (float)ht[1], zs);                                       \
      zs = fmaf(wt.z, (float)ht[2], zs);                                       \
      zs = fmaf(wt.w, (float)ht[3], zs);                                       \
      zs = fmaf(u_, (XT), zs + bz);                                            \
      const float a = mm * SIG2(zs) + dd;                                      \
      const float ai = qb0(a), af = qb1(a), ag = qb2(a), ao = qb3(a);          \
      cst = fmaf(af, cst, ai * ag);                                            \
      const float th = 2.f * SIG2(TWOL2E * cst) - 1.f;                         \
      if (g == 0) (HN)[myhid] = (_Float16)(ao * th);                           \
    }                                                                          \
    __syncthreads();                                                           \
  }

  for (int step = 0; step < TSTEPS; step += 2) {
    STEPB(hbuf[0], hbuf[1], xrow[step]);
    STEPB(hbuf[1], hbuf[0], xrow[step + 1]);
  }
#undef STEPB
#undef SIG2

  // out[bat] = dot(h_final, Wout) + bout; final h in hbuf[0]
  if (t < 128) {
    float a = 0.f;
    if (t < 100) a = (float)hbuf[0][t] * Wout[t];
    red[t] = a;
  }
  __syncthreads();
  if (t == 0) {
    float s = 0.f;
#pragma unroll
    for (int k = 0; k < 128; k++) s += red[k];
    out[bat] = s + bout[0];
  }
}

// ---------- launch ----------
extern "C" void kernel_launch(void* const* d_in, const int* in_sizes, int n_in,
                              void* d_out, int out_size, void* d_ws, size_t ws_size,
                              hipStream_t stream) {
  const float* x    = (const float*)d_in[0];   // (256,1024)
  const float* W1L  = (const float*)d_in[3];   // (1024,1024)
  const float* b1L  = (const float*)d_in[4];
  const float* W2L  = (const float*)d_in[7];   // (512,512)
  const float* b2L  = (const float*)d_in[8];
  const float* Wih3 = (const float*)d_in[15];  // (400,1)
  const float* Whh3 = (const float*)d_in[16];  // (400,100)
  const float* b3   = (const float*)d_in[17];  // (400,)
  const float* Wout = (const float*)d_in[18];  // (1,100)
  const float* bout = (const float*)d_in[19];  // (1,)
  float* out = (float*)d_out;                  // (256,)

  unsigned short* xl1b = (unsigned short*)d_ws;        // 256x512 bf16
  float* xl2 = (float*)(xl1b + (size_t)256 * 512);     // 256x256 f32
  _Float16* P = (_Float16*)(xl2 + (size_t)256 * 256);  // 400x128 fp16

  prep_whh<<<25, 256, 0, stream>>>(Whh3, b3, P);
  gemm_mfma_sig_pool<1, 1><<<dim3(16, 16), 256, 0, stream>>>(W1L, b1L, x, xl1b, 1024, 512, 1);
  gemm_mfma_sig_pool<1, 0><<<dim3(8, 16), 256, 0, stream>>>(W2L, b2L, xl1b, xl2, 512, 256, 0);
  lstm_mfma<<<256, 512, 0, stream>>>(xl2, P, Whh3, Wih3, b3, Wout, bout, out);
}